// Round 13
// baseline (267.752 us; speedup 1.0000x reference)
//
#include <hip/hip_runtime.h>
#include <hip/hip_bf16.h>

#define BATCH 8
#define NPTS 2048
#define KNNK 16
#define CH 64
#define CF 128
#define CA 256
#define CB 512
#define CCAT 640
#define CC 256
#define CD 128
#define CE 256
#define CG 512
#define NGRP 4
#define EPSF 1e-5f
#define GF_OFF (BATCH*CG)
#define P 8              // points per MFMA block (k_stats, k_main)
#define MROWS (P*KNNK)   // 128 rows
#define TM 64            // points per k_tail block

typedef __attribute__((ext_vector_type(8))) short short8v;
typedef __attribute__((ext_vector_type(4))) float f32x4;

// native RTNE f32->bf16 (compiler emits v_cvt_pk_bf16_f32)
__device__ inline short f2bf(float f) {
  __hip_bfloat16 h = __float2bfloat16(f);
  return *reinterpret_cast<short*>(&h);
}

// XOR-swizzled LDS element index (bf16 elements; flips 16B slot within 128B)
#define LIDX(r, c, ROW) ((r)*(ROW) + ((c) ^ (((r)&7)<<3)))

// pack W[O][ld] (f32, leading C cols used) into MFMA fragment-linear bf16
__device__ inline void pack_dev(const float* __restrict__ W, short* __restrict__ Wp,
                                int O, int C, int ld, int tid) {
  int KS = C >> 5;
  int total = (O >> 4) * KS * 64;
  if (tid >= total) return;
  int l = tid & 63;
  int fs = tid >> 6;
  int nt = fs / KS, ks = fs - nt * KS;
  int o = nt * 16 + (l & 15);
  int c = ks * 32 + (l >> 4) * 8;
  const float* src = W + (size_t)o * ld + c;
  short8v v;
#pragma unroll
  for (int j = 0; j < 8; ++j) v[j] = f2bf(src[j]);
  *(short8v*)&Wp[(size_t)tid * 8] = v;
}

// fused: knn (blocks 0..2047) + h-compute (2048..4095) + weight packs (4096..4195)
// knn and prep are data-independent; prep rides in knn's latency shadow.
__global__ __launch_bounds__(512)
void k_knn_prep(const float* __restrict__ x, int* __restrict__ idxout,
                const float* __restrict__ f, const float* __restrict__ Wit,
                const float* __restrict__ bit, float* __restrict__ h,
                const float* __restrict__ W1, short* __restrict__ W1p,
                const float* __restrict__ Wa, short* __restrict__ Wap,
                const float* __restrict__ Wb, short* __restrict__ Wbp,
                const float* __restrict__ Wc, short* __restrict__ WcLp,
                const float* __restrict__ Wd, short* __restrict__ Wdp,
                const float* __restrict__ We, short* __restrict__ Wep,
                const float* __restrict__ Wf, short* __restrict__ Wfp) {
  int blk = blockIdx.x;
  if (blk >= 2048) {
    if (blk < 4096) {
      int t = (blk - 2048) * 512 + threadIdx.x;   // covers 1048576
      int o = t & (CH - 1);
      int bn = t >> 6;
      int n = bn & (NPTS - 1);
      int b = bn >> 11;
      float f0 = f[(b*3 + 0)*NPTS + n];
      float f1 = f[(b*3 + 1)*NPTS + n];
      float f2 = f[(b*3 + 2)*NPTS + n];
      h[t] = f0*Wit[o*3+0] + f1*Wit[o*3+1] + f2*Wit[o*3+2] + bit[o];
    } else if (blk < 4100) pack_dev(W1, W1p, CF, CF, CF, (blk-4096)*512 + threadIdx.x);
    else if (blk < 4108) pack_dev(Wa, Wap, CA, CF, CF, (blk-4100)*512 + threadIdx.x);
    else if (blk < 4140) pack_dev(Wb, Wbp, CB, CA, CA, (blk-4108)*512 + threadIdx.x);
    else if (blk < 4148) pack_dev(Wc, WcLp, CC, CF, CCAT, (blk-4140)*512 + threadIdx.x);
    else if (blk < 4156) pack_dev(Wd, Wdp, CD, CC, CC, (blk-4148)*512 + threadIdx.x);
    else if (blk < 4164) pack_dev(We, Wep, CE, CD, CD, (blk-4156)*512 + threadIdx.x);
    else                 pack_dev(Wf, Wfp, CG, CE, CE, (blk-4164)*512 + threadIdx.x);
    return;
  }
  // ---- knn: one wave per query, 8 queries per block ----
  __shared__ float xs0[2112], xs1[2112], xs2[2112], sqs[2112];
  int b = blk >> 8;               // 256 blocks per batch
  int n0 = (blk & 255) * 8;
  int t = threadIdx.x;
  for (int i = t; i < NPTS; i += 512) {
    float x0 = x[(b*3 + 0)*NPTS + i];
    float x1 = x[(b*3 + 1)*NPTS + i];
    float x2 = x[(b*3 + 2)*NPTS + i];
    int a = (i >> 5)*33 + (i & 31);
    xs0[a] = x0; xs1[a] = x1; xs2[a] = x2;
    sqs[a] = __fadd_rn(__fadd_rn(__fmul_rn(x0,x0), __fmul_rn(x1,x1)), __fmul_rn(x2,x2));
  }
  __syncthreads();
  int lane = t & 63, wv = t >> 6;
  int q = n0 + wv;
  int qa = (q >> 5)*33 + (q & 31);
  float qx = xs0[qa], qy = xs1[qa], qz = xs2[qa];
  float sqq = sqs[qa];
  float d[32];
  int base = lane * 32;
#pragma unroll
  for (int jj = 0; jj < 32; ++jj) {
    int a = lane*33 + jj;
    float mx = xs0[a], my = xs1[a], mz = xs2[a];
    float dot = __fadd_rn(__fadd_rn(__fmul_rn(qx,mx), __fmul_rn(qy,my)), __fmul_rn(qz,mz));
    d[jj] = __fsub_rn(__fadd_rn(sqq, sqs[a]), __fadd_rn(dot, dot));
  }
  const float FINF = __builtin_inff();
  float sv0 = d[0]; int si0 = base;
#pragma unroll
  for (int jj = 1; jj < 16; ++jj)
    if (d[jj] < sv0) { sv0 = d[jj]; si0 = base + jj; }
  float sv1 = d[16]; int si1 = base + 16;
#pragma unroll
  for (int jj = 17; jj < 32; ++jj)
    if (d[jj] < sv1) { sv1 = d[jj]; si1 = base + jj; }
  int gsel = 0;
#pragma unroll
  for (int r = 0; r < KNNK; ++r) {
    float v = sv0; int i = si0;
    if (sv1 < v || (sv1 == v && si1 < i)) { v = sv1; i = si1; }
#pragma unroll
    for (int off = 32; off > 0; off >>= 1) {
      float v2 = __shfl_xor(v, off);
      int   i2 = __shfl_xor(i, off);
      if (v2 < v || (v2 == v && i2 < i)) { v = v2; i = i2; }
    }
    if (lane == r) gsel = i;
    int rem = ((i >> 5) == lane) ? (i & 31) : 64;
    if (rem < 16) {
      float nv = FINF; int ni = 0x7fffffff;
#pragma unroll
      for (int jj = 0; jj < 16; ++jj) {
        float dv = (jj == rem) ? FINF : d[jj];
        d[jj] = dv;
        if (dv < nv) { nv = dv; ni = base + jj; }
      }
      sv0 = nv; si0 = ni;
    } else if (rem < 32) {
      float nv = FINF; int ni = 0x7fffffff;
#pragma unroll
      for (int jj = 16; jj < 32; ++jj) {
        float dv = (jj == rem) ? FINF : d[jj];
        d[jj] = dv;
        if (dv < nv) { nv = dv; ni = base + jj; }
      }
      sv1 = nv; si1 = ni;
    }
  }
  if (lane < KNNK) idxout[(size_t)(b*NPTS + q)*KNNK + lane] = gsel;
}

// --- stage 128 edge-feature rows (8 points x 16 nbrs) into swizzled bf16 LDS ---
__device__ inline void stage_feat(short* featS, const float* __restrict__ h,
                                  const int* __restrict__ idx, int b, int n0, int t) {
  int r = t >> 1, cb = (t & 1) * 32;
  int p = r >> 4, kk = r & 15;
  int nbi = idx[(size_t)(b*NPTS + n0 + p)*KNNK + kk];
  const float* hq = h + (size_t)(b*NPTS + n0 + p)*CH;
  const float* hn = h + (size_t)(b*NPTS + nbi)*CH;
#pragma unroll
  for (int j = 0; j < 32; j += 8) {
    float4 q0 = *(const float4*)(hq + cb + j);
    float4 q1 = *(const float4*)(hq + cb + j + 4);
    float4 a0 = *(const float4*)(hn + cb + j);
    float4 a1 = *(const float4*)(hn + cb + j + 4);
    short8v dv, qv;
    dv[0]=f2bf(a0.x-q0.x); dv[1]=f2bf(a0.y-q0.y); dv[2]=f2bf(a0.z-q0.z); dv[3]=f2bf(a0.w-q0.w);
    dv[4]=f2bf(a1.x-q1.x); dv[5]=f2bf(a1.y-q1.y); dv[6]=f2bf(a1.z-q1.z); dv[7]=f2bf(a1.w-q1.w);
    qv[0]=f2bf(q0.x); qv[1]=f2bf(q0.y); qv[2]=f2bf(q0.z); qv[3]=f2bf(q0.w);
    qv[4]=f2bf(q1.x); qv[5]=f2bf(q1.y); qv[6]=f2bf(q1.z); qv[7]=f2bf(q1.w);
    *(short8v*)&featS[LIDX(r, cb + j, CF)] = dv;
    *(short8v*)&featS[LIDX(r, 64 + cb + j, CF)] = qv;
  }
}

// GEMM1 only, GroupNorm partial sums. Two-pass m (af[4][4]).
__global__ __launch_bounds__(256, 2)
void k_stats(const float* __restrict__ h, const int* __restrict__ idx,
             const short* __restrict__ W1p, float* __restrict__ partials) {
  __shared__ short featS[MROWS*CF];
  int blk = blockIdx.x;
  int b = blk >> 8;
  int n0 = (blk & 255) * P;
  int t = threadIdx.x;
  stage_feat(featS, h, idx, b, n0, t);
  __syncthreads();
  int lane = t & 63, wv = t >> 6;
  int r16 = lane & 15, g8 = (lane >> 4) * 8;
  float s = 0.f, ss = 0.f;
#pragma unroll
  for (int mh = 0; mh < 2; ++mh) {
    short8v af[4][4];
#pragma unroll
    for (int mm = 0; mm < 4; ++mm)
#pragma unroll
      for (int ks = 0; ks < 4; ++ks)
        af[mm][ks] = *(const short8v*)&featS[LIDX((mh*4+mm)*16 + r16, ks*32 + g8, CF)];
#pragma unroll
    for (int n = 0; n < 2; ++n) {
      int nt = 2*wv + n;
      short8v bfr[4];
#pragma unroll
      for (int ks = 0; ks < 4; ++ks)
        bfr[ks] = *(const short8v*)&W1p[(size_t)((nt*4 + ks)*64 + lane)*8];
#pragma unroll
      for (int mm = 0; mm < 4; ++mm) {
        f32x4 acc = {0.f, 0.f, 0.f, 0.f};
#pragma unroll
        for (int ks = 0; ks < 4; ++ks)
          acc = __builtin_amdgcn_mfma_f32_16x16x32_bf16(af[mm][ks], bfr[ks], acc, 0, 0, 0);
#pragma unroll
        for (int i = 0; i < 4; ++i) { s += acc[i]; ss += acc[i]*acc[i]; }
      }
    }
  }
#pragma unroll
  for (int off = 32; off > 0; off >>= 1) {
    s += __shfl_xor(s, off);
    ss += __shfl_xor(ss, off);
  }
  if (lane == 0) {
    partials[(size_t)(blk*NGRP + wv)*2 + 0] = s;
    partials[(size_t)(blk*NGRP + wv)*2 + 1] = ss;
  }
}

__global__ void k_reduce(const float* __restrict__ partials, float* __restrict__ stats) {
  int b = blockIdx.x >> 2, g = blockIdx.x & 3;
  int t = threadIdx.x;
  float s  = partials[(size_t)((b*256 + t)*NGRP + g)*2 + 0];
  float ss = partials[(size_t)((b*256 + t)*NGRP + g)*2 + 1];
  __shared__ float rs[256], rss[256];
  rs[t] = s; rss[t] = ss;
  __syncthreads();
  for (int st = 128; st > 0; st >>= 1) {
    if (t < st) { rs[t] += rs[t+st]; rss[t] += rss[t+st]; }
    __syncthreads();
  }
  if (t == 0) {
    const float cnt = (float)((size_t)NPTS * KNNK * 32);
    float mu = rs[0] / cnt;
    float var = rss[0] / cnt - mu*mu;
    stats[(b*NGRP+g)*2+0] = mu;
    stats[(b*NGRP+g)*2+1] = rsqrtf(var + EPSF);
  }
}

// k_main: R5-exact structure (P=8, 64KB LDS aliased, (256,2)) + native f2bf.
__global__ __launch_bounds__(256, 2)
void k_main(const float* __restrict__ h, const int* __restrict__ idx,
            const short* __restrict__ W1p, const float* __restrict__ gng,
            const float* __restrict__ gnb, const float* __restrict__ stats,
            const short* __restrict__ Wap, const float* __restrict__ ba,
            const short* __restrict__ Wbp, const float* __restrict__ bb,
            float* __restrict__ lbase, unsigned* __restrict__ gmaxU) {
  __shared__ short lds[MROWS*CA];     // 64 KB total
  short* featS = lds;                 // 32 KB
  short* ynS   = lds + MROWS*CF;      // 32 KB
  short* g1S   = lds;                 // 64 KB (overlays feat+yn)
  int blk = blockIdx.x;
  int b = blk >> 8;
  int n0 = (blk & 255) * P;
  int t = threadIdx.x;
  stage_feat(featS, h, idx, b, n0, t);
  __syncthreads();
  int lane = t & 63, wv = t >> 6;
  int r16 = lane & 15, g8 = (lane >> 4) * 8;
  int rowg = (lane >> 4) * 4;
  // ---- GEMM1: y = feat @ W1^T, GN affine + leaky -> ynS + lbase ----
  {
    short8v af[8][4];
#pragma unroll
    for (int m = 0; m < 8; ++m)
#pragma unroll
      for (int ks = 0; ks < 4; ++ks)
        af[m][ks] = *(const short8v*)&featS[LIDX(m*16 + r16, ks*32 + g8, CF)];
    float mu  = stats[(b*NGRP + wv)*2 + 0];
    float rsg = stats[(b*NGRP + wv)*2 + 1];
#pragma unroll
    for (int n = 0; n < 2; ++n) {
      int nt = 2*wv + n;
      int o = nt*16 + r16;
      short8v bfr[4];
#pragma unroll
      for (int ks = 0; ks < 4; ++ks)
        bfr[ks] = *(const short8v*)&W1p[(size_t)((nt*4 + ks)*64 + lane)*8];
      float ga = gng[o], bev = gnb[o];
#pragma unroll
      for (int m = 0; m < 8; ++m) {
        f32x4 acc = {0.f, 0.f, 0.f, 0.f};
#pragma unroll
        for (int ks = 0; ks < 4; ++ks)
          acc = __builtin_amdgcn_mfma_f32_16x16x32_bf16(af[m][ks], bfr[ks], acc, 0, 0, 0);
        float vmax = -3.0e38f;
#pragma unroll
        for (int i = 0; i < 4; ++i) {
          float v = (acc[i] - mu) * rsg * ga + bev;
          v = (v >= 0.f) ? v : 0.2f*v;
          vmax = fmaxf(vmax, v);
          ynS[LIDX(m*16 + rowg + i, o, CF)] = f2bf(v);
        }
        vmax = fmaxf(vmax, __shfl_xor(vmax, 16));
        vmax = fmaxf(vmax, __shfl_xor(vmax, 32));
        if (lane < 16) lbase[(size_t)(b*NPTS + n0 + m)*CF + o] = vmax;
      }
    }
  }
  __syncthreads();
  // ---- GEMM2: g1 = relu(yn @ Wa^T + ba) -> g1S (overlays feat/yn) ----
  {
    short8v yf[8][4];
#pragma unroll
    for (int m = 0; m < 8; ++m)
#pragma unroll
      for (int ks = 0; ks < 4; ++ks)
        yf[m][ks] = *(const short8v*)&ynS[LIDX(m*16 + r16, ks*32 + g8, CF)];
    __syncthreads();   // all waves have yn in regs before overlay write
#pragma unroll
    for (int nn = 0; nn < 4; ++nn) {
      int nt = wv*4 + nn;
      int o = nt*16 + r16;
      short8v bfr[4];
#pragma unroll
      for (int ks = 0; ks < 4; ++ks)
        bfr[ks] = *(const short8v*)&Wap[(size_t)((nt*4 + ks)*64 + lane)*8];
      float bav = ba[o];
#pragma unroll
      for (int m = 0; m < 8; ++m) {
        f32x4 acc = {0.f, 0.f, 0.f, 0.f};
#pragma unroll
        for (int ks = 0; ks < 4; ++ks)
          acc = __builtin_amdgcn_mfma_f32_16x16x32_bf16(yf[m][ks], bfr[ks], acc, 0, 0, 0);
#pragma unroll
        for (int i = 0; i < 4; ++i) {
          float v = fmaxf(acc[i] + bav, 0.f);
          g1S[LIDX(m*16 + rowg + i, o, CA)] = f2bf(v);
        }
      }
    }
  }
  __syncthreads();
  // ---- GEMM3: ks-outer, 2 passes of 4 nt; acc[4][8] stays register-resident ----
#pragma unroll
  for (int half = 0; half < 2; ++half) {
    f32x4 acc[4][8];
#pragma unroll
    for (int nn = 0; nn < 4; ++nn)
#pragma unroll
      for (int m = 0; m < 8; ++m) acc[nn][m] = (f32x4){0.f, 0.f, 0.f, 0.f};
#pragma unroll
    for (int ks = 0; ks < 8; ++ks) {
      short8v gfk[8];
#pragma unroll
      for (int m = 0; m < 8; ++m)
        gfk[m] = *(const short8v*)&g1S[LIDX(m*16 + r16, ks*32 + g8, CA)];
#pragma unroll
      for (int nn = 0; nn < 4; ++nn) {
        int nt = wv*8 + half*4 + nn;
        short8v bfr = *(const short8v*)&Wbp[(size_t)((nt*8 + ks)*64 + lane)*8];
#pragma unroll
        for (int m = 0; m < 8; ++m)
          acc[nn][m] = __builtin_amdgcn_mfma_f32_16x16x32_bf16(gfk[m], bfr, acc[nn][m], 0, 0, 0);
      }
    }
#pragma unroll
    for (int nn = 0; nn < 4; ++nn) {
      int nt = wv*8 + half*4 + nn;
      float b0 = bb[nt*16 + r16];
      float am = 0.f;   // relu fold
#pragma unroll
      for (int m = 0; m < 8; ++m)
#pragma unroll
        for (int i = 0; i < 4; ++i) am = fmaxf(am, acc[nn][m][i] + b0);
      am = fmaxf(am, __shfl_xor(am, 16));
      am = fmaxf(am, __shfl_xor(am, 32));
      if (lane < 16) atomicMax(&gmaxU[b*CG + nt*16 + lane], __float_as_uint(am));
    }
  }
}

// MFMA tail, 512 threads (8 waves, 2 waves/SIMD), gbias folded into prologue.
__global__ __launch_bounds__(512)
void k_tail(const float* __restrict__ lbase, const unsigned* __restrict__ gmaxU,
            const float* __restrict__ Wc, const float* __restrict__ bc,
            const short* __restrict__ WcLp,
            const short* __restrict__ Wdp, const float* __restrict__ bd,
            const short* __restrict__ Wep, const float* __restrict__ be,
            const short* __restrict__ Wfp, const float* __restrict__ bf,
            float* __restrict__ out, unsigned* __restrict__ glmaxU) {
  __shared__ short aS0[TM*CF];     // 16 KB: lbase, then lf2
  __shared__ short aS1[TM*CA];     // 32 KB: lf1, then gl1
  __shared__ float bceffS[CC];     // 1 KB
  int blk = blockIdx.x;
  int b = blk >> 5;                // 32 blocks per batch
  int n0 = (blk & 31) * TM;
  int t = threadIdx.x;
  int lane = t & 63, wv = t >> 6;
  // stage lbase: thread t -> row t&63, 16-col segment (t>>6)*16
  {
    int r = t & 63, cs = (t >> 6) * 16;
    const float* src = lbase + (size_t)(b*NPTS + n0 + r)*CF + cs;
#pragma unroll
    for (int j = 0; j < 16; j += 8) {
      float4 v0 = *(const float4*)(src + j);
      float4 v1 = *(const float4*)(src + j + 4);
      short8v pv;
      pv[0]=f2bf(v0.x); pv[1]=f2bf(v0.y); pv[2]=f2bf(v0.z); pv[3]=f2bf(v0.w);
      pv[4]=f2bf(v1.x); pv[5]=f2bf(v1.y); pv[6]=f2bf(v1.z); pv[7]=f2bf(v1.w);
      *(short8v*)&aS0[LIDX(r, cs + j, CF)] = pv;
    }
  }
  // per-block bceff: wave wv computes o = wv*32..wv*32+31 (lane-parallel dots)
  {
    float gm[8];
#pragma unroll
    for (int k = 0; k < 8; ++k) gm[k] = __uint_as_float(gmaxU[b*CG + lane + 64*k]);
    for (int j = 0; j < 32; ++j) {
      int o = wv*32 + j;
      const float* wrow = Wc + (size_t)o*CCAT + CF;
      float acc = 0.f;
#pragma unroll
      for (int k = 0; k < 8; ++k) acc += gm[k] * wrow[lane + 64*k];
#pragma unroll
      for (int off = 32; off > 0; off >>= 1) acc += __shfl_xor(acc, off);
      if (lane == 0) bceffS[o] = bc[o] + acc;
    }
  }
  __syncthreads();
  int r16 = lane & 15, g8 = (lane >> 4) * 8;
  int rowg = (lane >> 4) * 4;
  // ---- GEMM-c: lf1 = relu(aS0 @ WcL^T + bceff) -> aS1 (16 nt over 8 waves) ----
  {
    short8v af[4][4];
#pragma unroll
    for (int mt = 0; mt < 4; ++mt)
#pragma unroll
      for (int ks = 0; ks < 4; ++ks)
        af[mt][ks] = *(const short8v*)&aS0[LIDX(mt*16 + r16, ks*32 + g8, CF)];
#pragma unroll
    for (int nn = 0; nn < 2; ++nn) {
      int nt = wv*2 + nn;
      int o = nt*16 + r16;
      short8v bfr[4];
#pragma unroll
      for (int ks = 0; ks < 4; ++ks)
        bfr[ks] = *(const short8v*)&WcLp[(size_t)((nt*4 + ks)*64 + lane)*8];
      float bce = bceffS[o];
#pragma unroll
      for (int mt = 0; mt < 4; ++mt) {
        f32x4 acc = {0.f, 0.f, 0.f, 0.f};
#pragma unroll
        for (int ks = 0; ks < 4; ++ks)
          acc = __builtin_amdgcn_mfma_f32_16x16x32_bf16(af[mt][ks], bfr[ks], acc, 0, 0, 0);
#pragma unroll
        for (int i = 0; i < 4; ++i)
          aS1[LIDX(mt*16 + rowg + i, o, CA)] = f2bf(fmaxf(acc[i] + bce, 0.f));
      }
    }
  }
  __syncthreads();
  // ---- GEMM-d: lf2 = relu(aS1 @ Wd^T + bd) -> aS0 + global (8 nt, 1/wave) ----
  {
    short8v af[4][8];
#pragma unroll
    for (int mt = 0; mt < 4; ++mt)
#pragma unroll
      for (int ks = 0; ks < 8; ++ks)
        af[mt][ks] = *(const short8v*)&aS1[LIDX(mt*16 + r16, ks*32 + g8, CA)];
    {
      int nt = wv;
      int o = nt*16 + r16;
      short8v bfr[8];
#pragma unroll
      for (int ks = 0; ks < 8; ++ks)
        bfr[ks] = *(const short8v*)&Wdp[(size_t)((nt*8 + ks)*64 + lane)*8];
      float bdv = bd[o];
#pragma unroll
      for (int mt = 0; mt < 4; ++mt) {
        f32x4 acc = {0.f, 0.f, 0.f, 0.f};
#pragma unroll
        for (int ks = 0; ks < 8; ++ks)
          acc = __builtin_amdgcn_mfma_f32_16x16x32_bf16(af[mt][ks], bfr[ks], acc, 0, 0, 0);
#pragma unroll
        for (int i = 0; i < 4; ++i) {
          float v = fmaxf(acc[i] + bdv, 0.f);
          aS0[LIDX(mt*16 + rowg + i, o, CF)] = f2bf(v);
          out[GF_OFF + ((size_t)(b*CD + o))*NPTS + n0 + mt*16 + rowg + i] = v;
        }
      }
    }
  }
  __syncthreads();
  // ---- GEMM-e: gl1 = relu(aS0 @ We^T + be) -> aS1 (16 nt over 8 waves) ----
  {
    short8v af[4][4];
#pragma unroll
    for (int mt = 0; mt < 4; ++mt)
#pragma unroll
      for (int ks = 0; ks < 4; ++ks)
        af[mt][ks] = *(const short8v*)&aS0[LIDX(mt*16 + r16, ks*32 + g8, CF)];
#pragma unroll
    for (int nn = 0; nn < 2; ++nn) {
      int nt = wv*2 + nn;
      int o = nt*16 + r16;
      short8v bfr[4];
#pragma unroll
      for (int ks = 0; ks < 4; ++ks)
        bfr[ks] = *(const short8v*)&Wep[(size_t)((nt*4 + ks)*64 + lane)*8];
      float bev = be[o];
#pragma unroll
      for (int mt = 0; mt < 4; ++mt) {
        f32x4 acc = {0.f, 0.f, 0.f, 0.f};
#pragma unroll
        for (int ks = 0; ks < 4; ++ks)
          acc = __builtin_amdgcn_mfma_f32_16x16x32_bf16(af[mt][ks], bfr[ks], acc, 0, 0, 0);
#pragma unroll
        for (int i = 0; i < 4; ++i)
          aS1[LIDX(mt*16 + rowg + i, o, CA)] = f2bf(fmaxf(acc[i] + bev, 0.f));
      }
    }
  }
  __syncthreads();
  // ---- GEMM-f: gl2 max (32 nt over 8 waves) ----
  {
    short8v af[4][8];
#pragma unroll
    for (int mt = 0; mt < 4; ++mt)
#pragma unroll
      for (int ks = 0; ks < 8; ++ks)
        af[mt][ks] = *(const short8v*)&aS1[LIDX(mt*16 + r16, ks*32 + g8, CA)];
#pragma unroll
    for (int nn = 0; nn < 4; ++nn) {
      int nt = wv*4 + nn;
      short8v bfr[8];
#pragma unroll
      for (int ks = 0; ks < 8; ++ks)
        bfr[ks] = *(const short8v*)&Wfp[(size_t)((nt*8 + ks)*64 + lane)*8];
      float bfv = bf[nt*16 + r16];
      float am = 0.f;  // relu fold
#pragma unroll
      for (int mt = 0; mt < 4; ++mt) {
        f32x4 acc = {0.f, 0.f, 0.f, 0.f};
#pragma unroll
        for (int ks = 0; ks < 8; ++ks)
          acc = __builtin_amdgcn_mfma_f32_16x16x32_bf16(af[mt][ks], bfr[ks], acc, 0, 0, 0);
#pragma unroll
        for (int i = 0; i < 4; ++i) am = fmaxf(am, acc[i] + bfv);
      }
      am = fmaxf(am, __shfl_xor(am, 16));
      am = fmaxf(am, __shfl_xor(am, 32));
      if (lane < 16) atomicMax(&glmaxU[b*CG + nt*16 + lane], __float_as_uint(am));
    }
  }
}

__global__ void k_final(const unsigned* __restrict__ glmaxU, float* __restrict__ out) {
  int i = blockIdx.x*256 + threadIdx.x;
  if (i < BATCH*CG) out[i] = __uint_as_float(glmaxU[i]);
}

extern "C" void kernel_launch(void* const* d_in, const int* in_sizes, int n_in,
                              void* d_out, int out_size, void* d_ws, size_t ws_size,
                              hipStream_t stream) {
  const float* x   = (const float*)d_in[0];
  const float* f   = (const float*)d_in[1];
  const float* Wit = (const float*)d_in[2];
  const float* bit = (const float*)d_in[3];
  const float* W1  = (const float*)d_in[4];
  const float* gng = (const float*)d_in[5];
  const float* gnb = (const float*)d_in[6];
  const float* Wa  = (const float*)d_in[7];
  const float* ba  = (const float*)d_in[8];
  const float* Wb  = (const float*)d_in[9];
  const float* bb  = (const float*)d_in[10];
  const float* Wc  = (const float*)d_in[11];
  const float* bc  = (const float*)d_in[12];
  const float* Wd  = (const float*)d_in[13];
  const float* bd  = (const float*)d_in[14];
  const float* We  = (const float*)d_in[15];
  const float* be  = (const float*)d_in[16];
  const float* Wf  = (const float*)d_in[17];
  const float* bf  = (const float*)d_in[18];
  float* out = (float*)d_out;

  char* w = (char*)d_ws;
  size_t off = 0;
  auto alloc = [&](size_t bytes) {
    void* p = w + off; off += (bytes + 255) & ~(size_t)255; return p;
  };
  float* h        = (float*)alloc((size_t)BATCH*NPTS*CH*4);
  int*   idx      = (int*)  alloc((size_t)BATCH*NPTS*KNNK*4);
  short* W1p      = (short*)alloc((size_t)CF*CF*2);
  short* Wap      = (short*)alloc((size_t)CA*CF*2);
  short* Wbp      = (short*)alloc((size_t)CB*CA*2);
  short* WcLp     = (short*)alloc((size_t)CC*CF*2);
  short* Wdp      = (short*)alloc((size_t)CD*CC*2);
  short* Wep      = (short*)alloc((size_t)CE*CD*2);
  short* Wfp      = (short*)alloc((size_t)CG*CE*2);
  float* partials = (float*)alloc((size_t)(BATCH*NPTS/P)*NGRP*2*4);
  float* stats    = (float*)alloc((size_t)BATCH*NGRP*2*4);
  float* lbase    = (float*)alloc((size_t)BATCH*NPTS*CF*4);
  unsigned* gmaxU  = (unsigned*)alloc((size_t)BATCH*CG*4);
  unsigned* glmaxU = (unsigned*)alloc((size_t)BATCH*CG*4);

  hipMemsetAsync(gmaxU, 0, (size_t)BATCH*CG*4, stream);
  hipMemsetAsync(glmaxU, 0, (size_t)BATCH*CG*4, stream);

  k_knn_prep<<<4196, 512, 0, stream>>>(x, idx, f, Wit, bit, h, W1, W1p,
                                       Wa, Wap, Wb, Wbp, Wc, WcLp,
                                       Wd, Wdp, We, Wep, Wf, Wfp);
  k_stats<<<BATCH*NPTS/P, 256, 0, stream>>>(h, idx, W1p, partials);
  k_reduce<<<BATCH*NGRP, 256, 0, stream>>>(partials, stats);
  k_main<<<BATCH*NPTS/P, 256, 0, stream>>>(h, idx, W1p, gng, gnb, stats,
                                           Wap, ba, Wbp, bb, lbase, gmaxU);
  k_tail<<<BATCH*NPTS/TM, 512, 0, stream>>>(lbase, gmaxU, Wc, bc, WcLp, Wdp, bd,
                                            Wep, be, Wfp, bf, out, glmaxU);
  k_final<<<(BATCH*CG+255)/256, 256, 0, stream>>>(glmaxU, out);
}

// Round 14
// 255.091 us; speedup vs baseline: 1.0496x; 1.0496x over previous
//
#include <hip/hip_runtime.h>
#include <hip/hip_bf16.h>

#define BATCH 8
#define NPTS 2048
#define KNNK 16
#define CH 64
#define CF 128
#define CA 256
#define CB 512
#define CCAT 640
#define CC 256
#define CD 128
#define CE 256
#define CG 512
#define NGRP 4
#define EPSF 1e-5f
#define GF_OFF (BATCH*CG)
#define P 8              // points per MFMA block (k_stats, k_main)
#define MROWS (P*KNNK)   // 128 rows
#define TM 64            // points per k_tail block

typedef __attribute__((ext_vector_type(8))) short short8v;
typedef __attribute__((ext_vector_type(4))) float f32x4;

// native RTNE f32->bf16 (compiler emits v_cvt_pk_bf16_f32)
__device__ inline short f2bf(float f) {
  __hip_bfloat16 h = __float2bfloat16(f);
  return *reinterpret_cast<short*>(&h);
}

// XOR-swizzled LDS element index (bf16 elements; flips 16B slot within 128B)
#define LIDX(r, c, ROW) ((r)*(ROW) + ((c) ^ (((r)&7)<<3)))

// pack W[O][ld] (f32, leading C cols used) into MFMA fragment-linear bf16
__device__ inline void pack_dev(const float* __restrict__ W, short* __restrict__ Wp,
                                int O, int C, int ld, int tid) {
  int KS = C >> 5;
  int total = (O >> 4) * KS * 64;
  if (tid >= total) return;
  int l = tid & 63;
  int fs = tid >> 6;
  int nt = fs / KS, ks = fs - nt * KS;
  int o = nt * 16 + (l & 15);
  int c = ks * 32 + (l >> 4) * 8;
  const float* src = W + (size_t)o * ld + c;
  short8v v;
#pragma unroll
  for (int j = 0; j < 8; ++j) v[j] = f2bf(src[j]);
  *(short8v*)&Wp[(size_t)tid * 8] = v;
}

// fused prep: h-compute (blocks 0..4095) + 7 weight packs (blocks 4096..4295)
__global__ __launch_bounds__(256)
void k_prep(const float* __restrict__ f, const float* __restrict__ Wit,
            const float* __restrict__ bit, float* __restrict__ h,
            const float* __restrict__ W1, short* __restrict__ W1p,
            const float* __restrict__ Wa, short* __restrict__ Wap,
            const float* __restrict__ Wb, short* __restrict__ Wbp,
            const float* __restrict__ Wc, short* __restrict__ WcLp,
            const float* __restrict__ Wd, short* __restrict__ Wdp,
            const float* __restrict__ We, short* __restrict__ Wep,
            const float* __restrict__ Wf, short* __restrict__ Wfp) {
  int blk = blockIdx.x;
  if (blk < 4096) {
    int t = blk * 256 + threadIdx.x;   // covers BATCH*NPTS*CH = 1048576
    int o = t & (CH - 1);
    int bn = t >> 6;
    int n = bn & (NPTS - 1);
    int b = bn >> 11;
    float f0 = f[(b*3 + 0)*NPTS + n];
    float f1 = f[(b*3 + 1)*NPTS + n];
    float f2 = f[(b*3 + 2)*NPTS + n];
    h[t] = f0*Wit[o*3+0] + f1*Wit[o*3+1] + f2*Wit[o*3+2] + bit[o];
  } else if (blk < 4104) pack_dev(W1, W1p, CF, CF, CF, (blk-4096)*256 + threadIdx.x);
  else if (blk < 4120) pack_dev(Wa, Wap, CA, CF, CF, (blk-4104)*256 + threadIdx.x);
  else if (blk < 4184) pack_dev(Wb, Wbp, CB, CA, CA, (blk-4120)*256 + threadIdx.x);
  else if (blk < 4200) pack_dev(Wc, WcLp, CC, CF, CCAT, (blk-4184)*256 + threadIdx.x);
  else if (blk < 4216) pack_dev(Wd, Wdp, CD, CC, CC, (blk-4200)*256 + threadIdx.x);
  else if (blk < 4232) pack_dev(We, Wep, CE, CD, CD, (blk-4216)*256 + threadIdx.x);
  else                 pack_dev(Wf, Wfp, CG, CE, CE, (blk-4232)*256 + threadIdx.x);
}

// one wave per query, 8 queries per 512-thread block
__global__ __launch_bounds__(512)
void k_knn(const float* __restrict__ x, int* __restrict__ idxout) {
  __shared__ float xs0[2112], xs1[2112], xs2[2112], sqs[2112];
  int blk = blockIdx.x;
  int b = blk >> 8;               // 256 blocks per batch
  int n0 = (blk & 255) * 8;
  int t = threadIdx.x;
  for (int i = t; i < NPTS; i += 512) {
    float x0 = x[(b*3 + 0)*NPTS + i];
    float x1 = x[(b*3 + 1)*NPTS + i];
    float x2 = x[(b*3 + 2)*NPTS + i];
    int a = (i >> 5)*33 + (i & 31);
    xs0[a] = x0; xs1[a] = x1; xs2[a] = x2;
    sqs[a] = __fadd_rn(__fadd_rn(__fmul_rn(x0,x0), __fmul_rn(x1,x1)), __fmul_rn(x2,x2));
  }
  __syncthreads();
  int lane = t & 63, wv = t >> 6;
  int q = n0 + wv;
  int qa = (q >> 5)*33 + (q & 31);
  float qx = xs0[qa], qy = xs1[qa], qz = xs2[qa];
  float sqq = sqs[qa];
  float d[32];
  int base = lane * 32;
#pragma unroll
  for (int jj = 0; jj < 32; ++jj) {
    int a = lane*33 + jj;
    float mx = xs0[a], my = xs1[a], mz = xs2[a];
    float dot = __fadd_rn(__fadd_rn(__fmul_rn(qx,mx), __fmul_rn(qy,my)), __fmul_rn(qz,mz));
    d[jj] = __fsub_rn(__fadd_rn(sqq, sqs[a]), __fadd_rn(dot, dot));
  }
  const float FINF = __builtin_inff();
  float sv0 = d[0]; int si0 = base;
#pragma unroll
  for (int jj = 1; jj < 16; ++jj)
    if (d[jj] < sv0) { sv0 = d[jj]; si0 = base + jj; }
  float sv1 = d[16]; int si1 = base + 16;
#pragma unroll
  for (int jj = 17; jj < 32; ++jj)
    if (d[jj] < sv1) { sv1 = d[jj]; si1 = base + jj; }
  int gsel = 0;
#pragma unroll
  for (int r = 0; r < KNNK; ++r) {
    float v = sv0; int i = si0;
    if (sv1 < v || (sv1 == v && si1 < i)) { v = sv1; i = si1; }
#pragma unroll
    for (int off = 32; off > 0; off >>= 1) {
      float v2 = __shfl_xor(v, off);
      int   i2 = __shfl_xor(i, off);
      if (v2 < v || (v2 == v && i2 < i)) { v = v2; i = i2; }
    }
    if (lane == r) gsel = i;
    int rem = ((i >> 5) == lane) ? (i & 31) : 64;
    if (rem < 16) {
      float nv = FINF; int ni = 0x7fffffff;
#pragma unroll
      for (int jj = 0; jj < 16; ++jj) {
        float dv = (jj == rem) ? FINF : d[jj];
        d[jj] = dv;
        if (dv < nv) { nv = dv; ni = base + jj; }
      }
      sv0 = nv; si0 = ni;
    } else if (rem < 32) {
      float nv = FINF; int ni = 0x7fffffff;
#pragma unroll
      for (int jj = 16; jj < 32; ++jj) {
        float dv = (jj == rem) ? FINF : d[jj];
        d[jj] = dv;
        if (dv < nv) { nv = dv; ni = base + jj; }
      }
      sv1 = nv; si1 = ni;
    }
  }
  if (lane < KNNK) idxout[(size_t)(b*NPTS + q)*KNNK + lane] = gsel;
}

// --- stage 128 edge-feature rows (8 points x 16 nbrs) into swizzled bf16 LDS ---
__device__ inline void stage_feat(short* featS, const float* __restrict__ h,
                                  const int* __restrict__ idx, int b, int n0, int t) {
  int r = t >> 1, cb = (t & 1) * 32;
  int p = r >> 4, kk = r & 15;
  int nbi = idx[(size_t)(b*NPTS + n0 + p)*KNNK + kk];
  const float* hq = h + (size_t)(b*NPTS + n0 + p)*CH;
  const float* hn = h + (size_t)(b*NPTS + nbi)*CH;
#pragma unroll
  for (int j = 0; j < 32; j += 8) {
    float4 q0 = *(const float4*)(hq + cb + j);
    float4 q1 = *(const float4*)(hq + cb + j + 4);
    float4 a0 = *(const float4*)(hn + cb + j);
    float4 a1 = *(const float4*)(hn + cb + j + 4);
    short8v dv, qv;
    dv[0]=f2bf(a0.x-q0.x); dv[1]=f2bf(a0.y-q0.y); dv[2]=f2bf(a0.z-q0.z); dv[3]=f2bf(a0.w-q0.w);
    dv[4]=f2bf(a1.x-q1.x); dv[5]=f2bf(a1.y-q1.y); dv[6]=f2bf(a1.z-q1.z); dv[7]=f2bf(a1.w-q1.w);
    qv[0]=f2bf(q0.x); qv[1]=f2bf(q0.y); qv[2]=f2bf(q0.z); qv[3]=f2bf(q0.w);
    qv[4]=f2bf(q1.x); qv[5]=f2bf(q1.y); qv[6]=f2bf(q1.z); qv[7]=f2bf(q1.w);
    *(short8v*)&featS[LIDX(r, cb + j, CF)] = dv;
    *(short8v*)&featS[LIDX(r, 64 + cb + j, CF)] = qv;
  }
}

// GEMM1 only, GroupNorm partial sums. Two-pass m (af[4][4]).
__global__ __launch_bounds__(256, 2)
void k_stats(const float* __restrict__ h, const int* __restrict__ idx,
             const short* __restrict__ W1p, float* __restrict__ partials) {
  __shared__ short featS[MROWS*CF];
  int blk = blockIdx.x;
  int b = blk >> 8;
  int n0 = (blk & 255) * P;
  int t = threadIdx.x;
  stage_feat(featS, h, idx, b, n0, t);
  __syncthreads();
  int lane = t & 63, wv = t >> 6;
  int r16 = lane & 15, g8 = (lane >> 4) * 8;
  float s = 0.f, ss = 0.f;
#pragma unroll
  for (int mh = 0; mh < 2; ++mh) {
    short8v af[4][4];
#pragma unroll
    for (int mm = 0; mm < 4; ++mm)
#pragma unroll
      for (int ks = 0; ks < 4; ++ks)
        af[mm][ks] = *(const short8v*)&featS[LIDX((mh*4+mm)*16 + r16, ks*32 + g8, CF)];
#pragma unroll
    for (int n = 0; n < 2; ++n) {
      int nt = 2*wv + n;
      short8v bfr[4];
#pragma unroll
      for (int ks = 0; ks < 4; ++ks)
        bfr[ks] = *(const short8v*)&W1p[(size_t)((nt*4 + ks)*64 + lane)*8];
#pragma unroll
      for (int mm = 0; mm < 4; ++mm) {
        f32x4 acc = {0.f, 0.f, 0.f, 0.f};
#pragma unroll
        for (int ks = 0; ks < 4; ++ks)
          acc = __builtin_amdgcn_mfma_f32_16x16x32_bf16(af[mm][ks], bfr[ks], acc, 0, 0, 0);
#pragma unroll
        for (int i = 0; i < 4; ++i) { s += acc[i]; ss += acc[i]*acc[i]; }
      }
    }
  }
#pragma unroll
  for (int off = 32; off > 0; off >>= 1) {
    s += __shfl_xor(s, off);
    ss += __shfl_xor(ss, off);
  }
  if (lane == 0) {
    partials[(size_t)(blk*NGRP + wv)*2 + 0] = s;
    partials[(size_t)(blk*NGRP + wv)*2 + 1] = ss;
  }
}

__global__ void k_reduce(const float* __restrict__ partials, float* __restrict__ stats) {
  int b = blockIdx.x >> 2, g = blockIdx.x & 3;
  int t = threadIdx.x;
  float s  = partials[(size_t)((b*256 + t)*NGRP + g)*2 + 0];
  float ss = partials[(size_t)((b*256 + t)*NGRP + g)*2 + 1];
  __shared__ float rs[256], rss[256];
  rs[t] = s; rss[t] = ss;
  __syncthreads();
  for (int st = 128; st > 0; st >>= 1) {
    if (t < st) { rs[t] += rs[t+st]; rss[t] += rss[t+st]; }
    __syncthreads();
  }
  if (t == 0) {
    const float cnt = (float)((size_t)NPTS * KNNK * 32);
    float mu = rs[0] / cnt;
    float var = rss[0] / cnt - mu*mu;
    stats[(b*NGRP+g)*2+0] = mu;
    stats[(b*NGRP+g)*2+1] = rsqrtf(var + EPSF);
  }
}

// k_main: R5-exact structure (P=8, 64KB LDS aliased, (256,2)) + native f2bf.
__global__ __launch_bounds__(256, 2)
void k_main(const float* __restrict__ h, const int* __restrict__ idx,
            const short* __restrict__ W1p, const float* __restrict__ gng,
            const float* __restrict__ gnb, const float* __restrict__ stats,
            const short* __restrict__ Wap, const float* __restrict__ ba,
            const short* __restrict__ Wbp, const float* __restrict__ bb,
            float* __restrict__ lbase, unsigned* __restrict__ gmaxU) {
  __shared__ short lds[MROWS*CA];     // 64 KB total
  short* featS = lds;                 // 32 KB
  short* ynS   = lds + MROWS*CF;      // 32 KB
  short* g1S   = lds;                 // 64 KB (overlays feat+yn)
  int blk = blockIdx.x;
  int b = blk >> 8;
  int n0 = (blk & 255) * P;
  int t = threadIdx.x;
  stage_feat(featS, h, idx, b, n0, t);
  __syncthreads();
  int lane = t & 63, wv = t >> 6;
  int r16 = lane & 15, g8 = (lane >> 4) * 8;
  int rowg = (lane >> 4) * 4;
  // ---- GEMM1: y = feat @ W1^T, GN affine + leaky -> ynS + lbase ----
  {
    short8v af[8][4];
#pragma unroll
    for (int m = 0; m < 8; ++m)
#pragma unroll
      for (int ks = 0; ks < 4; ++ks)
        af[m][ks] = *(const short8v*)&featS[LIDX(m*16 + r16, ks*32 + g8, CF)];
    float mu  = stats[(b*NGRP + wv)*2 + 0];
    float rsg = stats[(b*NGRP + wv)*2 + 1];
#pragma unroll
    for (int n = 0; n < 2; ++n) {
      int nt = 2*wv + n;
      int o = nt*16 + r16;
      short8v bfr[4];
#pragma unroll
      for (int ks = 0; ks < 4; ++ks)
        bfr[ks] = *(const short8v*)&W1p[(size_t)((nt*4 + ks)*64 + lane)*8];
      float ga = gng[o], bev = gnb[o];
#pragma unroll
      for (int m = 0; m < 8; ++m) {
        f32x4 acc = {0.f, 0.f, 0.f, 0.f};
#pragma unroll
        for (int ks = 0; ks < 4; ++ks)
          acc = __builtin_amdgcn_mfma_f32_16x16x32_bf16(af[m][ks], bfr[ks], acc, 0, 0, 0);
        float vmax = -3.0e38f;
#pragma unroll
        for (int i = 0; i < 4; ++i) {
          float v = (acc[i] - mu) * rsg * ga + bev;
          v = (v >= 0.f) ? v : 0.2f*v;
          vmax = fmaxf(vmax, v);
          ynS[LIDX(m*16 + rowg + i, o, CF)] = f2bf(v);
        }
        vmax = fmaxf(vmax, __shfl_xor(vmax, 16));
        vmax = fmaxf(vmax, __shfl_xor(vmax, 32));
        if (lane < 16) lbase[(size_t)(b*NPTS + n0 + m)*CF + o] = vmax;
      }
    }
  }
  __syncthreads();
  // ---- GEMM2: g1 = relu(yn @ Wa^T + ba) -> g1S (overlays feat/yn) ----
  {
    short8v yf[8][4];
#pragma unroll
    for (int m = 0; m < 8; ++m)
#pragma unroll
      for (int ks = 0; ks < 4; ++ks)
        yf[m][ks] = *(const short8v*)&ynS[LIDX(m*16 + r16, ks*32 + g8, CF)];
    __syncthreads();   // all waves have yn in regs before overlay write
#pragma unroll
    for (int nn = 0; nn < 4; ++nn) {
      int nt = wv*4 + nn;
      int o = nt*16 + r16;
      short8v bfr[4];
#pragma unroll
      for (int ks = 0; ks < 4; ++ks)
        bfr[ks] = *(const short8v*)&Wap[(size_t)((nt*4 + ks)*64 + lane)*8];
      float bav = ba[o];
#pragma unroll
      for (int m = 0; m < 8; ++m) {
        f32x4 acc = {0.f, 0.f, 0.f, 0.f};
#pragma unroll
        for (int ks = 0; ks < 4; ++ks)
          acc = __builtin_amdgcn_mfma_f32_16x16x32_bf16(yf[m][ks], bfr[ks], acc, 0, 0, 0);
#pragma unroll
        for (int i = 0; i < 4; ++i) {
          float v = fmaxf(acc[i] + bav, 0.f);
          g1S[LIDX(m*16 + rowg + i, o, CA)] = f2bf(v);
        }
      }
    }
  }
  __syncthreads();
  // ---- GEMM3: ks-outer, 2 passes of 4 nt; acc[4][8] stays register-resident ----
#pragma unroll
  for (int half = 0; half < 2; ++half) {
    f32x4 acc[4][8];
#pragma unroll
    for (int nn = 0; nn < 4; ++nn)
#pragma unroll
      for (int m = 0; m < 8; ++m) acc[nn][m] = (f32x4){0.f, 0.f, 0.f, 0.f};
#pragma unroll
    for (int ks = 0; ks < 8; ++ks) {
      short8v gfk[8];
#pragma unroll
      for (int m = 0; m < 8; ++m)
        gfk[m] = *(const short8v*)&g1S[LIDX(m*16 + r16, ks*32 + g8, CA)];
#pragma unroll
      for (int nn = 0; nn < 4; ++nn) {
        int nt = wv*8 + half*4 + nn;
        short8v bfr = *(const short8v*)&Wbp[(size_t)((nt*8 + ks)*64 + lane)*8];
#pragma unroll
        for (int m = 0; m < 8; ++m)
          acc[nn][m] = __builtin_amdgcn_mfma_f32_16x16x32_bf16(gfk[m], bfr, acc[nn][m], 0, 0, 0);
      }
    }
#pragma unroll
    for (int nn = 0; nn < 4; ++nn) {
      int nt = wv*8 + half*4 + nn;
      float b0 = bb[nt*16 + r16];
      float am = 0.f;   // relu fold
#pragma unroll
      for (int m = 0; m < 8; ++m)
#pragma unroll
        for (int i = 0; i < 4; ++i) am = fmaxf(am, acc[nn][m][i] + b0);
      am = fmaxf(am, __shfl_xor(am, 16));
      am = fmaxf(am, __shfl_xor(am, 32));
      if (lane < 16) atomicMax(&gmaxU[b*CG + nt*16 + lane], __float_as_uint(am));
    }
  }
}

// per-batch effective bias, parallelized: 256 blocks (8 batches x 32 o-groups)
__global__ __launch_bounds__(256)
void k_gbias(const unsigned* __restrict__ gmaxU, const float* __restrict__ Wc,
             const float* __restrict__ bc, float* __restrict__ bceff) {
  __shared__ float gs[CB];
  int blk = blockIdx.x;
  int b = blk >> 5, og = blk & 31;   // 8 o-channels per block
  int t = threadIdx.x;
  int lane = t & 63, wv = t >> 6;
  for (int i = t; i < CB; i += 256) gs[i] = __uint_as_float(gmaxU[b*CG + i]);
  __syncthreads();
#pragma unroll
  for (int j = 0; j < 2; ++j) {
    int o = og*8 + wv*2 + j;
    float acc = 0.f;
#pragma unroll
    for (int c8 = 0; c8 < 8; ++c8) {
      int c = lane + c8*64;
      acc += gs[c] * Wc[(size_t)o*CCAT + CF + c];
    }
#pragma unroll
    for (int off = 32; off > 0; off >>= 1) acc += __shfl_xor(acc, off);
    if (lane == 0) bceff[b*CC + o] = bc[o] + acc;
  }
}

// MFMA tail, 512 threads (8 waves, 2 waves/SIMD); bceff precomputed by k_gbias.
__global__ __launch_bounds__(512)
void k_tail(const float* __restrict__ lbase, const float* __restrict__ bceff,
            const short* __restrict__ WcLp,
            const short* __restrict__ Wdp, const float* __restrict__ bd,
            const short* __restrict__ Wep, const float* __restrict__ be,
            const short* __restrict__ Wfp, const float* __restrict__ bf,
            float* __restrict__ out, unsigned* __restrict__ glmaxU) {
  __shared__ short aS0[TM*CF];     // 16 KB: lbase, then lf2
  __shared__ short aS1[TM*CA];     // 32 KB: lf1, then gl1
  int blk = blockIdx.x;
  int b = blk >> 5;                // 32 blocks per batch
  int n0 = (blk & 31) * TM;
  int t = threadIdx.x;
  int lane = t & 63, wv = t >> 6;
  // stage lbase: thread t -> row t&63, 16-col segment (t>>6)*16
  {
    int r = t & 63, cs = (t >> 6) * 16;
    const float* src = lbase + (size_t)(b*NPTS + n0 + r)*CF + cs;
#pragma unroll
    for (int j = 0; j < 16; j += 8) {
      float4 v0 = *(const float4*)(src + j);
      float4 v1 = *(const float4*)(src + j + 4);
      short8v pv;
      pv[0]=f2bf(v0.x); pv[1]=f2bf(v0.y); pv[2]=f2bf(v0.z); pv[3]=f2bf(v0.w);
      pv[4]=f2bf(v1.x); pv[5]=f2bf(v1.y); pv[6]=f2bf(v1.z); pv[7]=f2bf(v1.w);
      *(short8v*)&aS0[LIDX(r, cs + j, CF)] = pv;
    }
  }
  __syncthreads();
  int r16 = lane & 15, g8 = (lane >> 4) * 8;
  int rowg = (lane >> 4) * 4;
  // ---- GEMM-c: lf1 = relu(aS0 @ WcL^T + bceff) -> aS1 (16 nt over 8 waves) ----
  {
    short8v af[4][4];
#pragma unroll
    for (int mt = 0; mt < 4; ++mt)
#pragma unroll
      for (int ks = 0; ks < 4; ++ks)
        af[mt][ks] = *(const short8v*)&aS0[LIDX(mt*16 + r16, ks*32 + g8, CF)];
#pragma unroll
    for (int nn = 0; nn < 2; ++nn) {
      int nt = wv*2 + nn;
      int o = nt*16 + r16;
      short8v bfr[4];
#pragma unroll
      for (int ks = 0; ks < 4; ++ks)
        bfr[ks] = *(const short8v*)&WcLp[(size_t)((nt*4 + ks)*64 + lane)*8];
      float bce = bceff[b*CC + o];
#pragma unroll
      for (int mt = 0; mt < 4; ++mt) {
        f32x4 acc = {0.f, 0.f, 0.f, 0.f};
#pragma unroll
        for (int ks = 0; ks < 4; ++ks)
          acc = __builtin_amdgcn_mfma_f32_16x16x32_bf16(af[mt][ks], bfr[ks], acc, 0, 0, 0);
#pragma unroll
        for (int i = 0; i < 4; ++i)
          aS1[LIDX(mt*16 + rowg + i, o, CA)] = f2bf(fmaxf(acc[i] + bce, 0.f));
      }
    }
  }
  __syncthreads();
  // ---- GEMM-d: lf2 = relu(aS1 @ Wd^T + bd) -> aS0 + global (8 nt, 1/wave) ----
  {
    short8v af[4][8];
#pragma unroll
    for (int mt = 0; mt < 4; ++mt)
#pragma unroll
      for (int ks = 0; ks < 8; ++ks)
        af[mt][ks] = *(const short8v*)&aS1[LIDX(mt*16 + r16, ks*32 + g8, CA)];
    {
      int nt = wv;
      int o = nt*16 + r16;
      short8v bfr[8];
#pragma unroll
      for (int ks = 0; ks < 8; ++ks)
        bfr[ks] = *(const short8v*)&Wdp[(size_t)((nt*8 + ks)*64 + lane)*8];
      float bdv = bd[o];
#pragma unroll
      for (int mt = 0; mt < 4; ++mt) {
        f32x4 acc = {0.f, 0.f, 0.f, 0.f};
#pragma unroll
        for (int ks = 0; ks < 8; ++ks)
          acc = __builtin_amdgcn_mfma_f32_16x16x32_bf16(af[mt][ks], bfr[ks], acc, 0, 0, 0);
#pragma unroll
        for (int i = 0; i < 4; ++i) {
          float v = fmaxf(acc[i] + bdv, 0.f);
          aS0[LIDX(mt*16 + rowg + i, o, CF)] = f2bf(v);
          out[GF_OFF + ((size_t)(b*CD + o))*NPTS + n0 + mt*16 + rowg + i] = v;
        }
      }
    }
  }
  __syncthreads();
  // ---- GEMM-e: gl1 = relu(aS0 @ We^T + be) -> aS1 (16 nt over 8 waves) ----
  {
    short8v af[4][4];
#pragma unroll
    for (int mt = 0; mt < 4; ++mt)
#pragma unroll
      for (int ks = 0; ks < 4; ++ks)
        af[mt][ks] = *(const short8v*)&aS0[LIDX(mt*16 + r16, ks*32 + g8, CF)];
#pragma unroll
    for (int nn = 0; nn < 2; ++nn) {
      int nt = wv*2 + nn;
      int o = nt*16 + r16;
      short8v bfr[4];
#pragma unroll
      for (int ks = 0; ks < 4; ++ks)
        bfr[ks] = *(const short8v*)&Wep[(size_t)((nt*4 + ks)*64 + lane)*8];
      float bev = be[o];
#pragma unroll
      for (int mt = 0; mt < 4; ++mt) {
        f32x4 acc = {0.f, 0.f, 0.f, 0.f};
#pragma unroll
        for (int ks = 0; ks < 4; ++ks)
          acc = __builtin_amdgcn_mfma_f32_16x16x32_bf16(af[mt][ks], bfr[ks], acc, 0, 0, 0);
#pragma unroll
        for (int i = 0; i < 4; ++i)
          aS1[LIDX(mt*16 + rowg + i, o, CA)] = f2bf(fmaxf(acc[i] + bev, 0.f));
      }
    }
  }
  __syncthreads();
  // ---- GEMM-f: gl2 max (32 nt over 8 waves) ----
  {
    short8v af[4][8];
#pragma unroll
    for (int mt = 0; mt < 4; ++mt)
#pragma unroll
      for (int ks = 0; ks < 8; ++ks)
        af[mt][ks] = *(const short8v*)&aS1[LIDX(mt*16 + r16, ks*32 + g8, CA)];
#pragma unroll
    for (int nn = 0; nn < 4; ++nn) {
      int nt = wv*4 + nn;
      short8v bfr[8];
#pragma unroll
      for (int ks = 0; ks < 8; ++ks)
        bfr[ks] = *(const short8v*)&Wfp[(size_t)((nt*8 + ks)*64 + lane)*8];
      float bfv = bf[nt*16 + r16];
      float am = 0.f;  // relu fold
#pragma unroll
      for (int mt = 0; mt < 4; ++mt) {
        f32x4 acc = {0.f, 0.f, 0.f, 0.f};
#pragma unroll
        for (int ks = 0; ks < 8; ++ks)
          acc = __builtin_amdgcn_mfma_f32_16x16x32_bf16(af[mt][ks], bfr[ks], acc, 0, 0, 0);
#pragma unroll
        for (int i = 0; i < 4; ++i) am = fmaxf(am, acc[i] + bfv);
      }
      am = fmaxf(am, __shfl_xor(am, 16));
      am = fmaxf(am, __shfl_xor(am, 32));
      if (lane < 16) atomicMax(&glmaxU[b*CG + nt*16 + lane], __float_as_uint(am));
    }
  }
}

__global__ void k_final(const unsigned* __restrict__ glmaxU, float* __restrict__ out) {
  int i = blockIdx.x*256 + threadIdx.x;
  if (i < BATCH*CG) out[i] = __uint_as_float(glmaxU[i]);
}

extern "C" void kernel_launch(void* const* d_in, const int* in_sizes, int n_in,
                              void* d_out, int out_size, void* d_ws, size_t ws_size,
                              hipStream_t stream) {
  const float* x   = (const float*)d_in[0];
  const float* f   = (const float*)d_in[1];
  const float* Wit = (const float*)d_in[2];
  const float* bit = (const float*)d_in[3];
  const float* W1  = (const float*)d_in[4];
  const float* gng = (const float*)d_in[5];
  const float* gnb = (const float*)d_in[6];
  const float* Wa  = (const float*)d_in[7];
  const float* ba  = (const float*)d_in[8];
  const float* Wb  = (const float*)d_in[9];
  const float* bb  = (const float*)d_in[10];
  const float* Wc  = (const float*)d_in[11];
  const float* bc  = (const float*)d_in[12];
  const float* Wd  = (const float*)d_in[13];
  const float* bd  = (const float*)d_in[14];
  const float* We  = (const float*)d_in[15];
  const float* be  = (const float*)d_in[16];
  const float* Wf  = (const float*)d_in[17];
  const float* bf  = (const float*)d_in[18];
  float* out = (float*)d_out;

  char* w = (char*)d_ws;
  size_t off = 0;
  auto alloc = [&](size_t bytes) {
    void* p = w + off; off += (bytes + 255) & ~(size_t)255; return p;
  };
  float* h        = (float*)alloc((size_t)BATCH*NPTS*CH*4);
  int*   idx      = (int*)  alloc((size_t)BATCH*NPTS*KNNK*4);
  short* W1p      = (short*)alloc((size_t)CF*CF*2);
  short* Wap      = (short*)alloc((size_t)CA*CF*2);
  short* Wbp      = (short*)alloc((size_t)CB*CA*2);
  short* WcLp     = (short*)alloc((size_t)CC*CF*2);
  short* Wdp      = (short*)alloc((size_t)CD*CC*2);
  short* Wep      = (short*)alloc((size_t)CE*CD*2);
  short* Wfp      = (short*)alloc((size_t)CG*CE*2);
  float* bceff    = (float*)alloc((size_t)BATCH*CC*4);
  float* partials = (float*)alloc((size_t)(BATCH*NPTS/P)*NGRP*2*4);
  float* stats    = (float*)alloc((size_t)BATCH*NGRP*2*4);
  float* lbase    = (float*)alloc((size_t)BATCH*NPTS*CF*4);
  unsigned* gmaxU  = (unsigned*)alloc((size_t)BATCH*CG*4);
  unsigned* glmaxU = (unsigned*)alloc((size_t)BATCH*CG*4);

  hipMemsetAsync(gmaxU, 0, (size_t)BATCH*CG*4, stream);
  hipMemsetAsync(glmaxU, 0, (size_t)BATCH*CG*4, stream);

  k_prep<<<4296, 256, 0, stream>>>(f, Wit, bit, h, W1, W1p, Wa, Wap, Wb, Wbp,
                                   Wc, WcLp, Wd, Wdp, We, Wep, Wf, Wfp);
  k_knn<<<BATCH*NPTS/8, 512, 0, stream>>>(x, idx);
  k_stats<<<BATCH*NPTS/P, 256, 0, stream>>>(h, idx, W1p, partials);
  k_reduce<<<BATCH*NGRP, 256, 0, stream>>>(partials, stats);
  k_main<<<BATCH*NPTS/P, 256, 0, stream>>>(h, idx, W1p, gng, gnb, stats,
                                           Wap, ba, Wbp, bb, lbase, gmaxU);
  k_gbias<<<BATCH*32, 256, 0, stream>>>(gmaxU, Wc, bc, bceff);
  k_tail<<<BATCH*NPTS/TM, 512, 0, stream>>>(lbase, bceff, WcLp, Wdp, bd,
                                            Wep, be, Wfp, bf, out, glmaxU);
  k_final<<<(BATCH*CG+255)/256, 256, 0, stream>>>(glmaxU, out);
}